// Round 1
// baseline (2118.846 us; speedup 1.0000x reference)
//
#include <hip/hip_runtime.h>
#include <hip/hip_bf16.h>

#define B_SZ 1024
#define H_DIM 1536
#define H3 (3*H_DIM)
#define LMAX 32
#define BK 64
#define KIT (H_DIM/BK)   // 24
#define TEMP_INV 20.0f

typedef __attribute__((ext_vector_type(4))) float f32x4;
typedef __attribute__((ext_vector_type(8))) short short8;
typedef unsigned short u16;
typedef unsigned int u32;

__device__ __forceinline__ u16 f2bf(float f){
  union { float f; u32 u; } v; v.f = f;
  u32 r = (v.u + 0x7FFFu + ((v.u >> 16) & 1u)) >> 16;
  return (u16)r;
}
__device__ __forceinline__ u32 pack2(float lo, float hi){
  return (u32)f2bf(lo) | ((u32)f2bf(hi) << 16);
}

// ---------------- prep: convert weights/k to bf16, init h ----------------
__global__ void prep_kernel(const float* __restrict__ wih, const float* __restrict__ whh,
                            const float* __restrict__ kemb, const float* __restrict__ qemb,
                            u16* __restrict__ wih_bf, u16* __restrict__ whh_bf,
                            u16* __restrict__ k_bf, float* __restrict__ h_f32,
                            u16* __restrict__ h_snap)
{
  size_t o = ((size_t)blockIdx.x * 256 + threadIdx.x) * 4;
  if (o < (size_t)H3 * H_DIM) {
    float4 a = *(const float4*)(wih + o);
    *(uint2*)(wih_bf + o) = make_uint2(pack2(a.x,a.y), pack2(a.z,a.w));
    float4 b = *(const float4*)(whh + o);
    *(uint2*)(whh_bf + o) = make_uint2(pack2(b.x,b.y), pack2(b.z,b.w));
  }
  if (o < (size_t)B_SZ * H_DIM) {
    float4 k4 = *(const float4*)(kemb + o);
    *(uint2*)(k_bf + o) = make_uint2(pack2(k4.x,k4.y), pack2(k4.z,k4.w));
    float4 q4 = *(const float4*)(qemb + o);
    *(float4*)(h_f32 + o) = q4;
    *(uint2*)(h_snap + o) = make_uint2(pack2(q4.x,q4.y), pack2(q4.z,q4.w));
  }
}

// ---------------- snap: h_f32 -> bf16 snapshot (race-free GEMM operand) ----
__global__ void snap_kernel(const float* __restrict__ h_f32, u16* __restrict__ h_snap){
  size_t o = ((size_t)blockIdx.x * 256 + threadIdx.x) * 4;
  float4 a = *(const float4*)(h_f32 + o);
  *(uint2*)(h_snap + o) = make_uint2(pack2(a.x,a.y), pack2(a.z,a.w));
}

// ---------------- offsets: exclusive cumsum of lens ----------------
__global__ void offsets_kernel(const int* __restrict__ lens, int* __restrict__ offsets){
  __shared__ int s[B_SZ];
  int i = threadIdx.x;
  int v = lens[i];
  s[i] = v; __syncthreads();
  for (int off = 1; off < B_SZ; off <<= 1){
    int t = (i >= off) ? s[i-off] : 0;
    __syncthreads();
    s[i] += t;
    __syncthreads();
  }
  offsets[i] = s[i] - v;
}

// ---------------- active-row lists per step ----------------
__global__ void lists_kernel(const int* __restrict__ lens, int* __restrict__ lists,
                             int* __restrict__ counts){
  int t = blockIdx.x;      // step 0..31
  int i = threadIdx.x;
  __shared__ int s[B_SZ];
  int f = (lens[i] > t) ? 1 : 0;
  s[i] = f; __syncthreads();
  for (int off = 1; off < B_SZ; off <<= 1){
    int v = (i >= off) ? s[i-off] : 0;
    __syncthreads();
    s[i] += v;
    __syncthreads();
  }
  if (f) lists[t*B_SZ + s[i] - 1] = i;
  if (i == B_SZ-1) counts[t] = s[B_SZ-1];
}

// ---------------- fused GRU step: 6-slab GEMM + gates ----------------
// tile: 64 rows (active-list gather) x 64 cols of H; BK=64; 4 waves 2x2
__global__ __launch_bounds__(256, 2) void gru_step_kernel(
    const float* __restrict__ inpn, const u16* __restrict__ h_snap,
    const u16* __restrict__ wih_bf, const u16* __restrict__ whh_bf,
    const float* __restrict__ b_ih, const float* __restrict__ b_hh,
    const int* __restrict__ offsets, const int* __restrict__ lists,
    const int* __restrict__ counts, float* __restrict__ h_f32, int t)
{
  int cnt = counts[t];
  int bx = blockIdx.x;                 // row tile
  if (bx * 64 >= cnt) return;
  int ct = blockIdx.y;                 // col tile over H (24)
  const int* list = lists + t * B_SZ;

  __shared__ u16 lds[8 * 64 * 64];     // 64 KB: g0=x g1=h g2..7=W slabs
  char* ldsb = (char*)lds;

  int tid = threadIdx.x;
  int wid = tid >> 6, lane = tid & 63;
  int wm = wid >> 1, wn = wid & 1;
  int lrow = lane & 15, lkh = lane >> 4;

  f32x4 acc[6][2][2] = {};

  for (int kt = 0; kt < KIT; ++kt) {
    int k0 = kt * BK;
    // ---- stage (reg-staged, f32->bf16 convert for x) ----
    #pragma unroll
    for (int cc = 0; cc < 2; ++cc) {
      int c = tid + cc * 256;          // chunk id 0..511
      int row = c >> 3, slot = c & 7;
      int swz = slot ^ (row & 7);
      int ridx = bx * 64 + row; if (ridx >= cnt) ridx = cnt - 1;
      int grow = list[ridx];
      // x tile (gather + convert)
      {
        const float* src = inpn + ((size_t)(offsets[grow] + t)) * H_DIM + k0 + slot * 8;
        float4 a = *(const float4*)src;
        float4 b = *(const float4*)(src + 4);
        uint4 v; v.x = pack2(a.x,a.y); v.y = pack2(a.z,a.w);
        v.z = pack2(b.x,b.y); v.w = pack2(b.z,b.w);
        *(uint4*)(ldsb + row * 128 + (swz << 4)) = v;
      }
      // h tile (bf16 snapshot)
      {
        uint4 v = *(const uint4*)(h_snap + (size_t)grow * H_DIM + k0 + slot * 8);
        *(uint4*)(ldsb + 8192 + row * 128 + (swz << 4)) = v;
      }
      // 6 weight slabs
      #pragma unroll
      for (int s = 0; s < 6; ++s) {
        const u16* Wm = (s < 3) ? wih_bf : whh_bf;
        int wrow = (s % 3) * H_DIM + ct * 64 + row;
        uint4 v = *(const uint4*)(Wm + (size_t)wrow * H_DIM + k0 + slot * 8);
        *(uint4*)(ldsb + (2 + s) * 8192 + row * 128 + (swz << 4)) = v;
      }
    }
    __syncthreads();
    // ---- compute ----
    #pragma unroll
    for (int q = 0; q < 2; ++q) {
      short8 ax[2], ah[2], bw[6][2];
      int cslot = q * 4 + lkh;
      #pragma unroll
      for (int m = 0; m < 2; ++m) {
        int row = wm * 32 + m * 16 + lrow;
        int byte = row * 128 + ((cslot ^ (row & 7)) << 4);
        ax[m] = *(const short8*)(ldsb + byte);
        ah[m] = *(const short8*)(ldsb + 8192 + byte);
      }
      #pragma unroll
      for (int n = 0; n < 2; ++n) {
        int row = wn * 32 + n * 16 + lrow;
        int byte = row * 128 + ((cslot ^ (row & 7)) << 4);
        #pragma unroll
        for (int s = 0; s < 6; ++s)
          bw[s][n] = *(const short8*)(ldsb + (2 + s) * 8192 + byte);
      }
      #pragma unroll
      for (int s = 0; s < 6; ++s)
        #pragma unroll
        for (int m = 0; m < 2; ++m)
          #pragma unroll
          for (int n = 0; n < 2; ++n)
            acc[s][m][n] = __builtin_amdgcn_mfma_f32_16x16x32_bf16(
                (s < 3) ? ax[m] : ah[m], bw[s][n], acc[s][m][n], 0, 0, 0);
    }
    __syncthreads();
  }

  // ---- gate epilogue: h_new = (1-z)*n + z*h ----
  #pragma unroll
  for (int m = 0; m < 2; ++m) {
    #pragma unroll
    for (int n = 0; n < 2; ++n) {
      int lc = wn * 32 + n * 16 + lrow;
      int j = ct * 64 + lc;
      float bir = b_ih[j],          bhr = b_hh[j];
      float biz = b_ih[H_DIM + j],  bhz = b_hh[H_DIM + j];
      float bin_ = b_ih[2*H_DIM+j], bhn = b_hh[2*H_DIM + j];
      #pragma unroll
      for (int r4 = 0; r4 < 4; ++r4) {
        int lm = wm * 32 + m * 16 + lkh * 4 + r4;
        int ridx = bx * 64 + lm; if (ridx >= cnt) ridx = cnt - 1;
        int grow = list[ridx];
        float ir = acc[0][m][n][r4] + bir;
        float iz = acc[1][m][n][r4] + biz;
        float inn = acc[2][m][n][r4] + bin_;
        float hr = acc[3][m][n][r4] + bhr;
        float hz = acc[4][m][n][r4] + bhz;
        float hn = acc[5][m][n][r4] + bhn;
        float r = 1.f / (1.f + __expf(-(ir + hr)));
        float z = 1.f / (1.f + __expf(-(iz + hz)));
        float nn = tanhf(inn + r * hn);
        size_t hidx = (size_t)grow * H_DIM + j;
        float hold = h_f32[hidx];
        h_f32[hidx] = (1.f - z) * nn + z * hold;
      }
    }
  }
}

// ---------------- scores: (qemb/T) @ k^T, bf16 MFMA ----------------
__global__ __launch_bounds__(256, 2) void scores_kernel(
    const u16* __restrict__ q_bf, const u16* __restrict__ k_bf,
    float* __restrict__ scores)
{
  int bx = blockIdx.x, by = blockIdx.y;
  __shared__ u16 lds[2 * 64 * 64];
  char* ldsb = (char*)lds;
  int tid = threadIdx.x;
  int wid = tid >> 6, lane = tid & 63;
  int wm = wid >> 1, wn = wid & 1;
  int lrow = lane & 15, lkh = lane >> 4;
  f32x4 acc[2][2] = {};

  for (int kt = 0; kt < KIT; ++kt) {
    int k0 = kt * BK;
    #pragma unroll
    for (int cc = 0; cc < 2; ++cc) {
      int c = tid + cc * 256;
      int row = c >> 3, slot = c & 7;
      int swz = slot ^ (row & 7);
      uint4 va = *(const uint4*)(q_bf + (size_t)(bx * 64 + row) * H_DIM + k0 + slot * 8);
      *(uint4*)(ldsb + row * 128 + (swz << 4)) = va;
      uint4 vb = *(const uint4*)(k_bf + (size_t)(by * 64 + row) * H_DIM + k0 + slot * 8);
      *(uint4*)(ldsb + 8192 + row * 128 + (swz << 4)) = vb;
    }
    __syncthreads();
    #pragma unroll
    for (int q = 0; q < 2; ++q) {
      short8 a[2], b[2];
      int cslot = q * 4 + lkh;
      #pragma unroll
      for (int m = 0; m < 2; ++m) {
        int row = wm * 32 + m * 16 + lrow;
        a[m] = *(const short8*)(ldsb + row * 128 + ((cslot ^ (row & 7)) << 4));
      }
      #pragma unroll
      for (int n = 0; n < 2; ++n) {
        int row = wn * 32 + n * 16 + lrow;
        b[n] = *(const short8*)(ldsb + 8192 + row * 128 + ((cslot ^ (row & 7)) << 4));
      }
      #pragma unroll
      for (int m = 0; m < 2; ++m)
        #pragma unroll
        for (int n = 0; n < 2; ++n)
          acc[m][n] = __builtin_amdgcn_mfma_f32_16x16x32_bf16(a[m], b[n], acc[m][n], 0,0,0);
    }
    __syncthreads();
  }
  #pragma unroll
  for (int m = 0; m < 2; ++m)
    #pragma unroll
    for (int n = 0; n < 2; ++n) {
      int col = by * 64 + wn * 32 + n * 16 + lrow;
      #pragma unroll
      for (int r4 = 0; r4 < 4; ++r4) {
        int rowg = bx * 64 + wm * 32 + m * 16 + lkh * 4 + r4;
        scores[(size_t)rowg * B_SZ + col] = acc[m][n][r4] * TEMP_INV;
      }
    }
}

// ---------------- per-row logsumexp loss ----------------
__global__ void softmax_kernel(const float* __restrict__ scores, float* __restrict__ row_loss){
  int i = blockIdx.x;
  int tid = threadIdx.x;
  const float* row = scores + (size_t)i * B_SZ;
  __shared__ float red[4];
  float m = -INFINITY;
  for (int j = tid; j < B_SZ; j += 256) m = fmaxf(m, row[j]);
  for (int off = 32; off; off >>= 1) m = fmaxf(m, __shfl_xor(m, off));
  if ((tid & 63) == 0) red[tid >> 6] = m;
  __syncthreads();
  m = fmaxf(fmaxf(red[0], red[1]), fmaxf(red[2], red[3]));
  __syncthreads();
  float s = 0.f;
  for (int j = tid; j < B_SZ; j += 256) s += __expf(row[j] - m);
  for (int off = 32; off; off >>= 1) s += __shfl_xor(s, off);
  if ((tid & 63) == 0) red[tid >> 6] = s;
  __syncthreads();
  if (tid == 0) {
    float S = red[0] + red[1] + red[2] + red[3];
    row_loss[i] = m + __logf(S) - row[i];
  }
}

__global__ void final_kernel(const float* __restrict__ row_loss, float* __restrict__ out){
  __shared__ float s[B_SZ];
  int i = threadIdx.x;
  s[i] = row_loss[i]; __syncthreads();
  for (int off = 512; off; off >>= 1) {
    if (i < off) s[i] += s[i + off];
    __syncthreads();
  }
  if (i == 0) out[0] = s[0] * (1.0f / B_SZ);
}

// ---------------- launch ----------------
extern "C" void kernel_launch(void* const* d_in, const int* in_sizes, int n_in,
                              void* d_out, int out_size, void* d_ws, size_t ws_size,
                              hipStream_t stream) {
  const float* q_emb = (const float*)d_in[0];
  const float* k_emb = (const float*)d_in[1];
  const float* inpn  = (const float*)d_in[2];
  const int*   lens  = (const int*)d_in[3];
  const float* wih   = (const float*)d_in[4];
  const float* whh   = (const float*)d_in[5];
  const float* bih   = (const float*)d_in[6];
  const float* bhh   = (const float*)d_in[7];
  float* out = (float*)d_out;

  char* p = (char*)d_ws;
  auto alloc = [&](size_t bytes){ char* r = p; p += (bytes + 255) & ~(size_t)255; return r; };
  int* offsets   = (int*)alloc(B_SZ * 4);
  int* counts    = (int*)alloc(LMAX * 4);
  int* lists_    = (int*)alloc((size_t)LMAX * B_SZ * 4);
  float* h_f32   = (float*)alloc((size_t)B_SZ * H_DIM * 4);
  u16* h_snap    = (u16*)alloc((size_t)B_SZ * H_DIM * 2);
  u16* wih_bf    = (u16*)alloc((size_t)H3 * H_DIM * 2);
  u16* whh_bf    = (u16*)alloc((size_t)H3 * H_DIM * 2);
  u16* k_bf      = (u16*)alloc((size_t)B_SZ * H_DIM * 2);
  float* scores  = (float*)alloc((size_t)B_SZ * B_SZ * 4);
  float* row_loss= (float*)alloc(B_SZ * 4);
  if ((size_t)(p - (char*)d_ws) > ws_size) return;  // workspace too small

  prep_kernel<<<(H3 * H_DIM / 4 + 255) / 256, 256, 0, stream>>>(
      wih, whh, k_emb, q_emb, wih_bf, whh_bf, k_bf, h_f32, h_snap);
  offsets_kernel<<<1, B_SZ, 0, stream>>>(lens, offsets);
  lists_kernel<<<LMAX, B_SZ, 0, stream>>>(lens, lists_, counts);

  for (int t = 0; t < LMAX; ++t) {
    if (t > 0)
      snap_kernel<<<B_SZ * H_DIM / (4 * 256), 256, 0, stream>>>(h_f32, h_snap);
    gru_step_kernel<<<dim3(16, H_DIM / 64), 256, 0, stream>>>(
        inpn, h_snap, wih_bf, whh_bf, bih, bhh, offsets, lists_, counts, h_f32, t);
  }
  snap_kernel<<<B_SZ * H_DIM / (4 * 256), 256, 0, stream>>>(h_f32, h_snap);

  scores_kernel<<<dim3(B_SZ / 64, B_SZ / 64), 256, 0, stream>>>(h_snap, k_bf, scores);
  softmax_kernel<<<B_SZ, 256, 0, stream>>>(scores, row_loss);
  final_kernel<<<1, B_SZ, 0, stream>>>(row_loss, out);
}

// Round 2
// 1692.109 us; speedup vs baseline: 1.2522x; 1.2522x over previous
//
#include <hip/hip_runtime.h>
#include <hip/hip_bf16.h>

#define B_SZ 1024
#define H_DIM 1536
#define H3 (3*H_DIM)
#define LMAX 32
#define TEMP_INV 20.0f

typedef __attribute__((ext_vector_type(4))) float f32x4;
typedef __attribute__((ext_vector_type(8))) short short8;
typedef unsigned short u16;
typedef unsigned int u32;

__device__ __forceinline__ u16 f2bf(float f){
  union { float f; u32 u; } v; v.f = f;
  u32 r = (v.u + 0x7FFFu + ((v.u >> 16) & 1u)) >> 16;
  return (u16)r;
}
__device__ __forceinline__ u32 pack2(float lo, float hi){
  return (u32)f2bf(lo) | ((u32)f2bf(hi) << 16);
}
__device__ __forceinline__ float bf2f(u16 b){
  union { u32 u; float f; } v; v.u = ((u32)b) << 16; return v.f;
}
__device__ __forceinline__ float sigm(float x){ return 1.f / (1.f + __expf(-x)); }

__device__ __forceinline__ void gload_lds16(const void* g, void* l){
  __builtin_amdgcn_global_load_lds(
      (const __attribute__((address_space(1))) void*)g,
      (__attribute__((address_space(3))) void*)l, 16, 0, 0);
}

// ---------------- prep: weights/k -> bf16, h0 = bf16(q) ----------------
__global__ void prep_kernel(const float* __restrict__ wih, const float* __restrict__ whh,
                            const float* __restrict__ kemb, const float* __restrict__ qemb,
                            u16* __restrict__ wih_bf, u16* __restrict__ whh_bf,
                            u16* __restrict__ k_bf, u16* __restrict__ h0)
{
  size_t o = ((size_t)blockIdx.x * 256 + threadIdx.x) * 8;
  if (o < (size_t)H3 * H_DIM) {
    float4 a0 = *(const float4*)(wih + o), a1 = *(const float4*)(wih + o + 4);
    *(uint4*)(wih_bf + o) = make_uint4(pack2(a0.x,a0.y), pack2(a0.z,a0.w),
                                       pack2(a1.x,a1.y), pack2(a1.z,a1.w));
    float4 b0 = *(const float4*)(whh + o), b1 = *(const float4*)(whh + o + 4);
    *(uint4*)(whh_bf + o) = make_uint4(pack2(b0.x,b0.y), pack2(b0.z,b0.w),
                                       pack2(b1.x,b1.y), pack2(b1.z,b1.w));
  }
  if (o < (size_t)B_SZ * H_DIM) {
    float4 k0 = *(const float4*)(kemb + o), k1 = *(const float4*)(kemb + o + 4);
    *(uint4*)(k_bf + o) = make_uint4(pack2(k0.x,k0.y), pack2(k0.z,k0.w),
                                     pack2(k1.x,k1.y), pack2(k1.z,k1.w));
    float4 q0 = *(const float4*)(qemb + o), q1 = *(const float4*)(qemb + o + 4);
    *(uint4*)(h0 + o) = make_uint4(pack2(q0.x,q0.y), pack2(q0.z,q0.w),
                                   pack2(q1.x,q1.y), pack2(q1.z,q1.w));
  }
}

// ---------------- convert inpn f32 -> bf16 (zero-pad to Mpad) ----------------
__global__ void convx_kernel(const float* __restrict__ x, u16* __restrict__ x_bf, int total){
  size_t o = ((size_t)blockIdx.x * 256 + threadIdx.x) * 8;
  int row = (int)(o / H_DIM);
  uint4 v;
  if (row < total) {
    float4 a0 = *(const float4*)(x + o), a1 = *(const float4*)(x + o + 4);
    v = make_uint4(pack2(a0.x,a0.y), pack2(a0.z,a0.w), pack2(a1.x,a1.y), pack2(a1.z,a1.w));
  } else v = make_uint4(0,0,0,0);
  *(uint4*)(x_bf + o) = v;
}

// ---------------- offsets: exclusive cumsum of lens ----------------
__global__ void offsets_kernel(const int* __restrict__ lens, int* __restrict__ offsets){
  __shared__ int s[B_SZ];
  int i = threadIdx.x;
  int v = lens[i];
  s[i] = v; __syncthreads();
  for (int off = 1; off < B_SZ; off <<= 1){
    int t = (i >= off) ? s[i-off] : 0;
    __syncthreads();
    s[i] += t;
    __syncthreads();
  }
  offsets[i] = s[i] - v;
}

// ---------------- active-row lists per step ----------------
__global__ void lists_kernel(const int* __restrict__ lens, int* __restrict__ lists,
                             int* __restrict__ counts){
  int t = blockIdx.x;
  int i = threadIdx.x;
  __shared__ int s[B_SZ];
  int f = (lens[i] > t) ? 1 : 0;
  s[i] = f; __syncthreads();
  for (int off = 1; off < B_SZ; off <<= 1){
    int v = (i >= off) ? s[i-off] : 0;
    __syncthreads();
    s[i] += v;
    __syncthreads();
  }
  if (f) lists[t*B_SZ + s[i] - 1] = i;
  if (i == B_SZ-1) counts[t] = s[B_SZ-1];
}

// ---------------- GI = x_bf @ W_ih^T + b_ih  (128x128 tile, BK=64) ----------------
__global__ __launch_bounds__(256, 2) void gi_gemm_kernel(
    const u16* __restrict__ x_bf, const u16* __restrict__ wih_bf,
    const float* __restrict__ b_ih, u16* __restrict__ gi, int nblk_m)
{
  int nblk = nblk_m * 36;
  int id = blockIdx.x;
  int q8 = nblk >> 3, r8 = nblk & 7;
  int xcd = id & 7, off = id >> 3;
  int swz = (xcd < r8) ? (xcd * (q8 + 1) + off) : (r8 * (q8 + 1) + (xcd - r8) * q8 + off);
  int bx = swz / 36, by = swz % 36;

  __shared__ u16 lds[2 * 128 * 64];   // 32 KB: A then B
  char* ldsb = (char*)lds;
  int tid = threadIdx.x, wid = tid >> 6, lane = tid & 63;
  int wm = wid >> 1, wn = wid & 1;
  int lrow = lane & 15, lkh = lane >> 4;
  f32x4 acc[4][4] = {};

  for (int kt = 0; kt < 24; ++kt) {
    int k0 = kt * 64;
    #pragma unroll
    for (int it = 0; it < 8; ++it) {
      int cb = it * 256 + wid * 64;        // wave-uniform chunk base
      int c  = cb + lane;
      int isB = c >> 10;
      int cc  = c & 1023;
      int row = cc >> 3, slot = cc & 7;
      const u16* src = isB ? (wih_bf + (size_t)(by * 128 + row) * H_DIM)
                           : (x_bf  + (size_t)(bx * 128 + row) * H_DIM);
      src += k0 + ((slot ^ (row & 7)) << 3);
      gload_lds16(src, ldsb + (size_t)cb * 16);
    }
    __syncthreads();
    #pragma unroll
    for (int qq = 0; qq < 2; ++qq) {
      short8 a[4], b[4];
      int slot = qq * 4 + lkh;
      #pragma unroll
      for (int m = 0; m < 4; ++m) {
        int row = wm * 64 + m * 16 + lrow;
        a[m] = *(const short8*)(ldsb + row * 128 + ((slot ^ (row & 7)) << 4));
      }
      #pragma unroll
      for (int n = 0; n < 4; ++n) {
        int row = wn * 64 + n * 16 + lrow;
        b[n] = *(const short8*)(ldsb + 16384 + row * 128 + ((slot ^ (row & 7)) << 4));
      }
      #pragma unroll
      for (int m = 0; m < 4; ++m)
        #pragma unroll
        for (int n = 0; n < 4; ++n)
          acc[m][n] = __builtin_amdgcn_mfma_f32_16x16x32_bf16(a[m], b[n], acc[m][n], 0,0,0);
    }
    __syncthreads();
  }
  #pragma unroll
  for (int n = 0; n < 4; ++n) {
    int j = by * 128 + wn * 64 + n * 16 + lrow;
    float bias = b_ih[j];
    #pragma unroll
    for (int m = 0; m < 4; ++m)
      #pragma unroll
      for (int r4 = 0; r4 < 4; ++r4) {
        int rowg = bx * 128 + wm * 64 + m * 16 + lkh * 4 + r4;
        gi[(size_t)rowg * 4608 + j] = f2bf(acc[m][n][r4] + bias);
      }
  }
}

// ---------------- per-step: GH = h @ W_hh^T (3 slabs) + gates ----------------
__global__ __launch_bounds__(256, 2) void gh_step_kernel(
    const u16* __restrict__ h_cur, u16* __restrict__ h_nxt,
    const u16* __restrict__ whh_bf, const u16* __restrict__ gi,
    const float* __restrict__ b_hh,
    const int* __restrict__ offsets, const int* __restrict__ lists,
    const int* __restrict__ counts, int t)
{
  int cnt = counts[t];
  int bid = blockIdx.x;                          // 0..383
  int ct = 3 * (bid & 7) + ((bid >> 3) % 3);     // XCD-pinned col tile
  int bx = bid / 24;
  if (bx * 64 >= cnt) return;
  const int* list = lists + t * B_SZ;

  __shared__ u16 lds[4 * 64 * 64];   // 32 KB: h, W_r, W_z, W_n
  char* ldsb = (char*)lds;
  int tid = threadIdx.x, wid = tid >> 6, lane = tid & 63;
  int wm = wid >> 1, wn = wid & 1;
  int lrow = lane & 15, lkh = lane >> 4;
  f32x4 acc[3][2][2] = {};

  for (int kt = 0; kt < 24; ++kt) {
    int k0 = kt * 64;
    #pragma unroll
    for (int it = 0; it < 8; ++it) {
      int cb = it * 256 + wid * 64;
      int c  = cb + lane;
      int tile = c >> 9;             // 0=h, 1..3=W slabs
      int cc   = c & 511;
      int row = cc >> 3, slot = cc & 7;
      const u16* src;
      if (tile == 0) {
        int ridx = bx * 64 + row; if (ridx >= cnt) ridx = cnt - 1;
        src = h_cur + (size_t)list[ridx] * H_DIM;
      } else {
        src = whh_bf + (size_t)((tile - 1) * H_DIM + ct * 64 + row) * H_DIM;
      }
      src += k0 + ((slot ^ (row & 7)) << 3);
      gload_lds16(src, ldsb + (size_t)cb * 16);
    }
    __syncthreads();
    #pragma unroll
    for (int qq = 0; qq < 2; ++qq) {
      short8 ah[2], bw[3][2];
      int slot = qq * 4 + lkh;
      #pragma unroll
      for (int m = 0; m < 2; ++m) {
        int row = wm * 32 + m * 16 + lrow;
        ah[m] = *(const short8*)(ldsb + row * 128 + ((slot ^ (row & 7)) << 4));
      }
      #pragma unroll
      for (int n = 0; n < 2; ++n) {
        int row = wn * 32 + n * 16 + lrow;
        int byte = row * 128 + ((slot ^ (row & 7)) << 4);
        #pragma unroll
        for (int s = 0; s < 3; ++s)
          bw[s][n] = *(const short8*)(ldsb + (1 + s) * 8192 + byte);
      }
      #pragma unroll
      for (int s = 0; s < 3; ++s)
        #pragma unroll
        for (int m = 0; m < 2; ++m)
          #pragma unroll
          for (int n = 0; n < 2; ++n)
            acc[s][m][n] = __builtin_amdgcn_mfma_f32_16x16x32_bf16(
                ah[m], bw[s][n], acc[s][m][n], 0, 0, 0);
    }
    __syncthreads();
  }

  // gates
  #pragma unroll
  for (int n = 0; n < 2; ++n) {
    int lc = wn * 32 + n * 16 + lrow;
    int j = ct * 64 + lc;
    float bhr = b_hh[j], bhz = b_hh[H_DIM + j], bhn = b_hh[2*H_DIM + j];
    #pragma unroll
    for (int m = 0; m < 2; ++m)
      #pragma unroll
      for (int r4 = 0; r4 < 4; ++r4) {
        int lm = wm * 32 + m * 16 + lkh * 4 + r4;
        int ridx = bx * 64 + lm; if (ridx >= cnt) ridx = cnt - 1;
        int grow = list[ridx];
        size_t gr = (size_t)(offsets[grow] + t) * 4608;
        float gir = bf2f(gi[gr + j]);
        float giz = bf2f(gi[gr + H_DIM + j]);
        float gin = bf2f(gi[gr + 2*H_DIM + j]);
        float r = sigm(gir + acc[0][m][n][r4] + bhr);
        float z = sigm(giz + acc[1][m][n][r4] + bhz);
        float nn = tanhf(gin + r * (acc[2][m][n][r4] + bhn));
        float hold = bf2f(h_cur[(size_t)grow * H_DIM + j]);
        h_nxt[(size_t)grow * H_DIM + j] = f2bf((1.f - z) * nn + z * hold);
      }
  }
}

// ---------------- scores: (h_final/T) @ k^T ----------------
__global__ __launch_bounds__(256, 2) void scores_kernel(
    const u16* __restrict__ h0, const u16* __restrict__ h1,
    const int* __restrict__ lens, const u16* __restrict__ k_bf,
    float* __restrict__ scores)
{
  int bx = blockIdx.x, by = blockIdx.y;
  __shared__ u16 lds[2 * 64 * 64];
  char* ldsb = (char*)lds;
  int tid = threadIdx.x, wid = tid >> 6, lane = tid & 63;
  int wm = wid >> 1, wn = wid & 1;
  int lrow = lane & 15, lkh = lane >> 4;
  f32x4 acc[2][2] = {};

  for (int kt = 0; kt < 24; ++kt) {
    int k0 = kt * 64;
    #pragma unroll
    for (int it = 0; it < 4; ++it) {
      int cb = it * 256 + wid * 64;
      int c  = cb + lane;
      int isB = c >> 9;
      int cc  = c & 511;
      int row = cc >> 3, slot = cc & 7;
      const u16* src;
      if (!isB) {
        int g = bx * 64 + row;
        src = ((lens[g] & 1) ? h1 : h0) + (size_t)g * H_DIM;
      } else {
        src = k_bf + (size_t)(by * 64 + row) * H_DIM;
      }
      src += k0 + ((slot ^ (row & 7)) << 3);
      gload_lds16(src, ldsb + (size_t)cb * 16);
    }
    __syncthreads();
    #pragma unroll
    for (int qq = 0; qq < 2; ++qq) {
      short8 a[2], b[2];
      int slot = qq * 4 + lkh;
      #pragma unroll
      for (int m = 0; m < 2; ++m) {
        int row = wm * 32 + m * 16 + lrow;
        a[m] = *(const short8*)(ldsb + row * 128 + ((slot ^ (row & 7)) << 4));
      }
      #pragma unroll
      for (int n = 0; n < 2; ++n) {
        int row = wn * 32 + n * 16 + lrow;
        b[n] = *(const short8*)(ldsb + 8192 + row * 128 + ((slot ^ (row & 7)) << 4));
      }
      #pragma unroll
      for (int m = 0; m < 2; ++m)
        #pragma unroll
        for (int n = 0; n < 2; ++n)
          acc[m][n] = __builtin_amdgcn_mfma_f32_16x16x32_bf16(a[m], b[n], acc[m][n], 0,0,0);
    }
    __syncthreads();
  }
  #pragma unroll
  for (int m = 0; m < 2; ++m)
    #pragma unroll
    for (int n = 0; n < 2; ++n) {
      int col = by * 64 + wn * 32 + n * 16 + lrow;
      #pragma unroll
      for (int r4 = 0; r4 < 4; ++r4) {
        int rowg = bx * 64 + wm * 32 + m * 16 + lkh * 4 + r4;
        scores[(size_t)rowg * B_SZ + col] = acc[m][n][r4] * TEMP_INV;
      }
    }
}

// ---------------- per-row logsumexp loss ----------------
__global__ void softmax_kernel(const float* __restrict__ scores, float* __restrict__ row_loss){
  int i = blockIdx.x;
  int tid = threadIdx.x;
  const float* row = scores + (size_t)i * B_SZ;
  __shared__ float red[4];
  float m = -INFINITY;
  for (int j = tid; j < B_SZ; j += 256) m = fmaxf(m, row[j]);
  for (int off = 32; off; off >>= 1) m = fmaxf(m, __shfl_xor(m, off));
  if ((tid & 63) == 0) red[tid >> 6] = m;
  __syncthreads();
  m = fmaxf(fmaxf(red[0], red[1]), fmaxf(red[2], red[3]));
  __syncthreads();
  float s = 0.f;
  for (int j = tid; j < B_SZ; j += 256) s += __expf(row[j] - m);
  for (int off = 32; off; off >>= 1) s += __shfl_xor(s, off);
  if ((tid & 63) == 0) red[tid >> 6] = s;
  __syncthreads();
  if (tid == 0) {
    float S = red[0] + red[1] + red[2] + red[3];
    row_loss[i] = m + __logf(S) - row[i];
  }
}

__global__ void final_kernel(const float* __restrict__ row_loss, float* __restrict__ out){
  __shared__ float s[B_SZ];
  int i = threadIdx.x;
  s[i] = row_loss[i]; __syncthreads();
  for (int off = 512; off; off >>= 1) {
    if (i < off) s[i] += s[i + off];
    __syncthreads();
  }
  if (i == 0) out[0] = s[0] * (1.0f / B_SZ);
}

// ---------------- launch ----------------
extern "C" void kernel_launch(void* const* d_in, const int* in_sizes, int n_in,
                              void* d_out, int out_size, void* d_ws, size_t ws_size,
                              hipStream_t stream) {
  const float* q_emb = (const float*)d_in[0];
  const float* k_emb = (const float*)d_in[1];
  const float* inpn  = (const float*)d_in[2];
  const int*   lens  = (const int*)d_in[3];
  const float* wih   = (const float*)d_in[4];
  const float* whh   = (const float*)d_in[5];
  const float* bih   = (const float*)d_in[6];
  const float* bhh   = (const float*)d_in[7];
  float* out = (float*)d_out;

  int total  = in_sizes[2] / H_DIM;
  int mtiles = (total + 127) / 128;
  int Mpad   = mtiles * 128;

  char* p = (char*)d_ws;
  auto alloc = [&](size_t bytes){ char* r = p; p += (bytes + 255) & ~(size_t)255; return r; };
  int* offsets   = (int*)alloc(B_SZ * 4);
  int* counts    = (int*)alloc(LMAX * 4);
  int* lists_    = (int*)alloc((size_t)LMAX * B_SZ * 4);
  u16* hbuf0     = (u16*)alloc((size_t)B_SZ * H_DIM * 2);
  u16* hbuf1     = (u16*)alloc((size_t)B_SZ * H_DIM * 2);
  u16* wih_bf    = (u16*)alloc((size_t)H3 * H_DIM * 2);
  u16* whh_bf    = (u16*)alloc((size_t)H3 * H_DIM * 2);
  u16* k_bf      = (u16*)alloc((size_t)B_SZ * H_DIM * 2);
  u16* x_bf      = (u16*)alloc((size_t)Mpad * H_DIM * 2);
  u16* gi        = (u16*)alloc((size_t)Mpad * H3 * 2);
  float* scores  = (float*)alloc((size_t)B_SZ * B_SZ * 4);
  float* row_loss= (float*)alloc(B_SZ * 4);
  if ((size_t)(p - (char*)d_ws) > ws_size) return;  // workspace too small (loud fail)

  prep_kernel<<<(H3 * H_DIM / 8) / 256, 256, 0, stream>>>(
      wih, whh, k_emb, q_emb, wih_bf, whh_bf, k_bf, hbuf0);
  convx_kernel<<<((size_t)Mpad * H_DIM / 8) / 256, 256, 0, stream>>>(inpn, x_bf, total);
  offsets_kernel<<<1, B_SZ, 0, stream>>>(lens, offsets);
  lists_kernel<<<LMAX, B_SZ, 0, stream>>>(lens, lists_, counts);

  gi_gemm_kernel<<<mtiles * 36, 256, 0, stream>>>(x_bf, wih_bf, bih, gi, mtiles);

  for (int t = 0; t < LMAX; ++t) {
    u16* hc = (t & 1) ? hbuf1 : hbuf0;
    u16* hn = (t & 1) ? hbuf0 : hbuf1;
    gh_step_kernel<<<384, 256, 0, stream>>>(
        hc, hn, whh_bf, gi, bhh, offsets, lists_, counts, t);
  }

  scores_kernel<<<dim3(B_SZ / 64, B_SZ / 64), 256, 0, stream>>>(
      hbuf0, hbuf1, lens, k_bf, scores);
  softmax_kernel<<<B_SZ, 256, 0, stream>>>(scores, row_loss);
  final_kernel<<<1, B_SZ, 0, stream>>>(row_loss, out);
}

// Round 3
// 1686.395 us; speedup vs baseline: 1.2564x; 1.0034x over previous
//
#include <hip/hip_runtime.h>
#include <hip/hip_bf16.h>

#define B_SZ 1024
#define H_DIM 1536
#define H3 (3*H_DIM)
#define LMAX 32
#define TEMP_INV 20.0f

typedef __attribute__((ext_vector_type(4))) float f32x4;
typedef __attribute__((ext_vector_type(8))) short short8;
typedef unsigned short u16;
typedef unsigned int u32;

__device__ __forceinline__ u16 f2bf(float f){
  union { float f; u32 u; } v; v.f = f;
  u32 r = (v.u + 0x7FFFu + ((v.u >> 16) & 1u)) >> 16;
  return (u16)r;
}
__device__ __forceinline__ u32 pack2(float lo, float hi){
  return (u32)f2bf(lo) | ((u32)f2bf(hi) << 16);
}
__device__ __forceinline__ float bf2f(u16 b){
  union { u32 u; float f; } v; v.u = ((u32)b) << 16; return v.f;
}
__device__ __forceinline__ float sigm(float x){ return 1.f / (1.f + __expf(-x)); }

__device__ __forceinline__ void gload_lds16(const void* g, void* l){
  __builtin_amdgcn_global_load_lds(
      (const __attribute__((address_space(1))) void*)g,
      (__attribute__((address_space(3))) void*)l, 16, 0, 0);
}

// ---------------- prep: weights/k -> bf16, h0 = bf16(q) ----------------
__global__ void prep_kernel(const float* __restrict__ wih, const float* __restrict__ whh,
                            const float* __restrict__ kemb, const float* __restrict__ qemb,
                            u16* __restrict__ wih_bf, u16* __restrict__ whh_bf,
                            u16* __restrict__ k_bf, u16* __restrict__ h0)
{
  size_t o = ((size_t)blockIdx.x * 256 + threadIdx.x) * 8;
  if (o < (size_t)H3 * H_DIM) {
    float4 a0 = *(const float4*)(wih + o), a1 = *(const float4*)(wih + o + 4);
    *(uint4*)(wih_bf + o) = make_uint4(pack2(a0.x,a0.y), pack2(a0.z,a0.w),
                                       pack2(a1.x,a1.y), pack2(a1.z,a1.w));
    float4 b0 = *(const float4*)(whh + o), b1 = *(const float4*)(whh + o + 4);
    *(uint4*)(whh_bf + o) = make_uint4(pack2(b0.x,b0.y), pack2(b0.z,b0.w),
                                       pack2(b1.x,b1.y), pack2(b1.z,b1.w));
  }
  if (o < (size_t)B_SZ * H_DIM) {
    float4 k0 = *(const float4*)(kemb + o), k1 = *(const float4*)(kemb + o + 4);
    *(uint4*)(k_bf + o) = make_uint4(pack2(k0.x,k0.y), pack2(k0.z,k0.w),
                                     pack2(k1.x,k1.y), pack2(k1.z,k1.w));
    float4 q0 = *(const float4*)(qemb + o), q1 = *(const float4*)(qemb + o + 4);
    *(uint4*)(h0 + o) = make_uint4(pack2(q0.x,q0.y), pack2(q0.z,q0.w),
                                   pack2(q1.x,q1.y), pack2(q1.z,q1.w));
  }
}

// ---------------- convert inpn f32 -> bf16 (zero-pad to Mpad) ----------------
__global__ void convx_kernel(const float* __restrict__ x, u16* __restrict__ x_bf, int total){
  size_t o = ((size_t)blockIdx.x * 256 + threadIdx.x) * 8;
  int row = (int)(o / H_DIM);
  uint4 v;
  if (row < total) {
    float4 a0 = *(const float4*)(x + o), a1 = *(const float4*)(x + o + 4);
    v = make_uint4(pack2(a0.x,a0.y), pack2(a0.z,a0.w), pack2(a1.x,a1.y), pack2(a1.z,a1.w));
  } else v = make_uint4(0,0,0,0);
  *(uint4*)(x_bf + o) = v;
}

// ---------------- offsets: exclusive cumsum of lens ----------------
__global__ void offsets_kernel(const int* __restrict__ lens, int* __restrict__ offsets){
  __shared__ int s[B_SZ];
  int i = threadIdx.x;
  int v = lens[i];
  s[i] = v; __syncthreads();
  for (int off = 1; off < B_SZ; off <<= 1){
    int t = (i >= off) ? s[i-off] : 0;
    __syncthreads();
    s[i] += t;
    __syncthreads();
  }
  offsets[i] = s[i] - v;
}

// ---------------- active-row lists per step ----------------
__global__ void lists_kernel(const int* __restrict__ lens, int* __restrict__ lists,
                             int* __restrict__ counts){
  int t = blockIdx.x;
  int i = threadIdx.x;
  __shared__ int s[B_SZ];
  int f = (lens[i] > t) ? 1 : 0;
  s[i] = f; __syncthreads();
  for (int off = 1; off < B_SZ; off <<= 1){
    int v = (i >= off) ? s[i-off] : 0;
    __syncthreads();
    s[i] += v;
    __syncthreads();
  }
  if (f) lists[t*B_SZ + s[i] - 1] = i;
  if (i == B_SZ-1) counts[t] = s[B_SZ-1];
}

// ---------------- GI = x_bf @ W_ih^T + b_ih  (128x128 tile, BK=64) ----------------
__global__ __launch_bounds__(256, 2) void gi_gemm_kernel(
    const u16* __restrict__ x_bf, const u16* __restrict__ wih_bf,
    const float* __restrict__ b_ih, u16* __restrict__ gi, int nblk_m)
{
  int nblk = nblk_m * 36;
  int id = blockIdx.x;
  int q8 = nblk >> 3, r8 = nblk & 7;
  int xcd = id & 7, off = id >> 3;
  int swz = (xcd < r8) ? (xcd * (q8 + 1) + off) : (r8 * (q8 + 1) + (xcd - r8) * q8 + off);
  int bx = swz / 36, by = swz % 36;

  __shared__ u16 lds[2 * 128 * 64];   // 32 KB: A then B
  char* ldsb = (char*)lds;
  int tid = threadIdx.x, wid = tid >> 6, lane = tid & 63;
  int wm = wid >> 1, wn = wid & 1;
  int lrow = lane & 15, lkh = lane >> 4;
  f32x4 acc[4][4] = {};

  for (int kt = 0; kt < 24; ++kt) {
    int k0 = kt * 64;
    #pragma unroll
    for (int it = 0; it < 8; ++it) {
      int cb = it * 256 + wid * 64;        // wave-uniform chunk base
      int c  = cb + lane;
      int isB = c >> 10;
      int cc  = c & 1023;
      int row = cc >> 3, slot = cc & 7;
      const u16* src = isB ? (wih_bf + (size_t)(by * 128 + row) * H_DIM)
                           : (x_bf  + (size_t)(bx * 128 + row) * H_DIM);
      src += k0 + ((slot ^ (row & 7)) << 3);
      gload_lds16(src, ldsb + (size_t)cb * 16);
    }
    __syncthreads();
    #pragma unroll
    for (int qq = 0; qq < 2; ++qq) {
      short8 a[4], b[4];
      int slot = qq * 4 + lkh;
      #pragma unroll
      for (int m = 0; m < 4; ++m) {
        int row = wm * 64 + m * 16 + lrow;
        a[m] = *(const short8*)(ldsb + row * 128 + ((slot ^ (row & 7)) << 4));
      }
      #pragma unroll
      for (int n = 0; n < 4; ++n) {
        int row = wn * 64 + n * 16 + lrow;
        b[n] = *(const short8*)(ldsb + 16384 + row * 128 + ((slot ^ (row & 7)) << 4));
      }
      #pragma unroll
      for (int m = 0; m < 4; ++m)
        #pragma unroll
        for (int n = 0; n < 4; ++n)
          acc[m][n] = __builtin_amdgcn_mfma_f32_16x16x32_bf16(a[m], b[n], acc[m][n], 0,0,0);
    }
    __syncthreads();
  }
  #pragma unroll
  for (int n = 0; n < 4; ++n) {
    int j = by * 128 + wn * 64 + n * 16 + lrow;
    float bias = b_ih[j];
    #pragma unroll
    for (int m = 0; m < 4; ++m)
      #pragma unroll
      for (int r4 = 0; r4 < 4; ++r4) {
        int rowg = bx * 128 + wm * 64 + m * 16 + lkh * 4 + r4;
        gi[(size_t)rowg * 4608 + j] = f2bf(acc[m][n][r4] + bias);
      }
  }
}

// ---------------- per-step: GH = h @ W_hh^T (3 slabs) + gates ----------------
// BM=128 rows x BN=64 cols, BK=64, 512 threads (8 waves 4m x 2n),
// double-buffered LDS (2 x 40 KB) with next-tile prefetch (T3-minimum 2-phase).
// 192 blocks = 8 XCD x 3 ct x 8 bx; each XCD's 3 W col-slabs (1.77 MB) stay L2-resident.
__global__ __launch_bounds__(512, 4) void gh_step_kernel(
    const u16* __restrict__ h_cur, u16* __restrict__ h_nxt,
    const u16* __restrict__ whh_bf, const u16* __restrict__ gi,
    const float* __restrict__ b_hh,
    const int* __restrict__ offsets, const int* __restrict__ lists,
    const int* __restrict__ counts, int t)
{
  int cnt = counts[t];
  int bid = blockIdx.x;                 // 0..191
  int x8 = bid & 7, jj = bid >> 3;      // XCD id, 0..23
  int ct = x8 * 3 + (jj >> 3);          // col tile 0..23 (64 cols each)
  int bx = jj & 7;                      // row tile 0..7 (128 rows each)
  if (bx * 128 >= cnt) return;
  const int* list = lists + t * B_SZ;

  __shared__ u16 lds[2 * 20480];        // 2 x 40 KB: [A 16K | Wr 8K | Wz 8K | Wn 8K]
  char* ldsb = (char*)lds;

  int tid = threadIdx.x, wid = tid >> 6, lane = tid & 63;
  int wm = wid >> 1, wn = wid & 1;      // 4m x 2n wave grid
  int lrow = lane & 15, lkh = lane >> 4;
  f32x4 acc[3][2][2] = {};

  // stage K-tile kt into buffer buf (40960 B = 2560 x 16B chunks, 5/thread)
  auto STAGE = [&](int buf, int kt){
    int k0 = kt * 64;
    char* base = ldsb + buf * 40960;
    #pragma unroll
    for (int it = 0; it < 5; ++it) {
      int cb = it * 512 + wid * 64;     // wave-uniform chunk base
      int c  = cb + lane;
      const u16* src;
      if (c < 1024) {                   // A: h rows (gather via active list)
        int row = c >> 3, slot = c & 7;
        int ridx = bx * 128 + row; if (ridx >= cnt) ridx = cnt - 1;
        src = h_cur + (size_t)list[ridx] * H_DIM + k0 + ((slot ^ (row & 7)) << 3);
      } else {                          // W slabs
        int w = c - 1024;
        int slab = w >> 9, row = (w >> 3) & 63, slot = w & 7;
        src = whh_bf + (size_t)(slab * H_DIM + ct * 64 + row) * H_DIM
              + k0 + ((slot ^ (row & 7)) << 3);
      }
      gload_lds16(src, base + (size_t)cb * 16);
    }
  };

  auto COMPUTE = [&](int buf){
    char* base = ldsb + buf * 40960;
    #pragma unroll
    for (int qq = 0; qq < 2; ++qq) {
      short8 ah[2], bw[3][2];
      int slot = qq * 4 + lkh;
      #pragma unroll
      for (int m = 0; m < 2; ++m) {
        int row = wm * 32 + m * 16 + lrow;
        ah[m] = *(const short8*)(base + row * 128 + ((slot ^ (row & 7)) << 4));
      }
      #pragma unroll
      for (int n = 0; n < 2; ++n) {
        int row = wn * 32 + n * 16 + lrow;
        int byte = row * 128 + ((slot ^ (row & 7)) << 4);
        #pragma unroll
        for (int s = 0; s < 3; ++s)
          bw[s][n] = *(const short8*)(base + 16384 + s * 8192 + byte);
      }
      #pragma unroll
      for (int s = 0; s < 3; ++s)
        #pragma unroll
        for (int m = 0; m < 2; ++m)
          #pragma unroll
          for (int n = 0; n < 2; ++n)
            acc[s][m][n] = __builtin_amdgcn_mfma_f32_16x16x32_bf16(
                ah[m], bw[s][n], acc[s][m][n], 0, 0, 0);
    }
  };

  STAGE(0, 0);
  __syncthreads();                      // drains the prologue stage
  int cur = 0;
  for (int kt = 0; kt < 24; ++kt) {
    if (kt + 1 < 24) STAGE(cur ^ 1, kt + 1);  // prefetch flies under compute
    COMPUTE(cur);
    __syncthreads();                    // drains vmcnt (prefetch) + lgkm; reuses bufs safely
    cur ^= 1;
  }

  // gates
  #pragma unroll
  for (int n = 0; n < 2; ++n) {
    int lc = wn * 32 + n * 16 + lrow;
    int j = ct * 64 + lc;
    float bhr = b_hh[j], bhz = b_hh[H_DIM + j], bhn = b_hh[2*H_DIM + j];
    #pragma unroll
    for (int m = 0; m < 2; ++m)
      #pragma unroll
      for (int r4 = 0; r4 < 4; ++r4) {
        int lm = wm * 32 + m * 16 + lkh * 4 + r4;
        int ridx = bx * 128 + lm;
        if (ridx < cnt) {
          int grow = list[ridx];
          size_t gr = (size_t)(offsets[grow] + t) * 4608;
          float gir = bf2f(gi[gr + j]);
          float giz = bf2f(gi[gr + H_DIM + j]);
          float gin = bf2f(gi[gr + 2*H_DIM + j]);
          float r = sigm(gir + acc[0][m][n][r4] + bhr);
          float z = sigm(giz + acc[1][m][n][r4] + bhz);
          float nn = tanhf(gin + r * (acc[2][m][n][r4] + bhn));
          float hold = bf2f(h_cur[(size_t)grow * H_DIM + j]);
          h_nxt[(size_t)grow * H_DIM + j] = f2bf((1.f - z) * nn + z * hold);
        }
      }
  }
}

// ---------------- scores: (h_final/T) @ k^T ----------------
__global__ __launch_bounds__(256, 2) void scores_kernel(
    const u16* __restrict__ h0, const u16* __restrict__ h1,
    const int* __restrict__ lens, const u16* __restrict__ k_bf,
    float* __restrict__ scores)
{
  int bx = blockIdx.x, by = blockIdx.y;
  __shared__ u16 lds[2 * 64 * 64];
  char* ldsb = (char*)lds;
  int tid = threadIdx.x, wid = tid >> 6, lane = tid & 63;
  int wm = wid >> 1, wn = wid & 1;
  int lrow = lane & 15, lkh = lane >> 4;
  f32x4 acc[2][2] = {};

  for (int kt = 0; kt < 24; ++kt) {
    int k0 = kt * 64;
    #pragma unroll
    for (int it = 0; it < 4; ++it) {
      int cb = it * 256 + wid * 64;
      int c  = cb + lane;
      int isB = c >> 9;
      int cc  = c & 511;
      int row = cc >> 3, slot = cc & 7;
      const u16* src;
      if (!isB) {
        int g = bx * 64 + row;
        src = ((lens[g] & 1) ? h1 : h0) + (size_t)g * H_DIM;
      } else {
        src = k_bf + (size_t)(by * 64 + row) * H_DIM;
      }
      src += k0 + ((slot ^ (row & 7)) << 3);
      gload_lds16(src, ldsb + (size_t)cb * 16);
    }
    __syncthreads();
    #pragma unroll
    for (int qq = 0; qq < 2; ++qq) {
      short8 a[2], b[2];
      int slot = qq * 4 + lkh;
      #pragma unroll
      for (int m = 0; m < 2; ++m) {
        int row = wm * 32 + m * 16 + lrow;
        a[m] = *(const short8*)(ldsb + row * 128 + ((slot ^ (row & 7)) << 4));
      }
      #pragma unroll
      for (int n = 0; n < 2; ++n) {
        int row = wn * 32 + n * 16 + lrow;
        b[n] = *(const short8*)(ldsb + 8192 + row * 128 + ((slot ^ (row & 7)) << 4));
      }
      #pragma unroll
      for (int m = 0; m < 2; ++m)
        #pragma unroll
        for (int n = 0; n < 2; ++n)
          acc[m][n] = __builtin_amdgcn_mfma_f32_16x16x32_bf16(a[m], b[n], acc[m][n], 0,0,0);
    }
    __syncthreads();
  }
  #pragma unroll
  for (int m = 0; m < 2; ++m)
    #pragma unroll
    for (int n = 0; n < 2; ++n) {
      int col = by * 64 + wn * 32 + n * 16 + lrow;
      #pragma unroll
      for (int r4 = 0; r4 < 4; ++r4) {
        int rowg = bx * 64 + wm * 32 + m * 16 + lkh * 4 + r4;
        scores[(size_t)rowg * B_SZ + col] = acc[m][n][r4] * TEMP_INV;
      }
    }
}

// ---------------- per-row logsumexp loss ----------------
__global__ void softmax_kernel(const float* __restrict__ scores, float* __restrict__ row_loss){
  int i = blockIdx.x;
  int tid = threadIdx.x;
  const float* row = scores + (size_t)i * B_SZ;
  __shared__ float red[4];
  float m = -INFINITY;
  for (int j = tid; j < B_SZ; j += 256) m = fmaxf(m, row[j]);
  for (int off = 32; off; off >>= 1) m = fmaxf(m, __shfl_xor(m, off));
  if ((tid & 63) == 0) red[tid >> 6] = m;
  __syncthreads();
  m = fmaxf(fmaxf(red[0], red[1]), fmaxf(red[2], red[3]));
  __syncthreads();
  float s = 0.f;
  for (int j = tid; j < B_SZ; j += 256) s += __expf(row[j] - m);
  for (int off = 32; off; off >>= 1) s += __shfl_xor(s, off);
  if ((tid & 63) == 0) red[tid >> 6] = s;
  __syncthreads();
  if (tid == 0) {
    float S = red[0] + red[1] + red[2] + red[3];
    row_loss[i] = m + __logf(S) - row[i];
  }
}

__global__ void final_kernel(const float* __restrict__ row_loss, float* __restrict__ out){
  __shared__ float s[B_SZ];
  int i = threadIdx.x;
  s[i] = row_loss[i]; __syncthreads();
  for (int off = 512; off; off >>= 1) {
    if (i < off) s[i] += s[i + off];
    __syncthreads();
  }
  if (i == 0) out[0] = s[0] * (1.0f / B_SZ);
}

// ---------------- launch ----------------
extern "C" void kernel_launch(void* const* d_in, const int* in_sizes, int n_in,
                              void* d_out, int out_size, void* d_ws, size_t ws_size,
                              hipStream_t stream) {
  const float* q_emb = (const float*)d_in[0];
  const float* k_emb = (const float*)d_in[1];
  const float* inpn  = (const float*)d_in[2];
  const int*   lens  = (const int*)d_in[3];
  const float* wih   = (const float*)d_in[4];
  const float* whh   = (const float*)d_in[5];
  const float* bih   = (const float*)d_in[6];
  const float* bhh   = (const float*)d_in[7];
  float* out = (float*)d_out;

  int total  = in_sizes[2] / H_DIM;
  int mtiles = (total + 127) / 128;
  int Mpad   = mtiles * 128;

  char* p = (char*)d_ws;
  auto alloc = [&](size_t bytes){ char* r = p; p += (bytes + 255) & ~(size_t)255; return r; };
  int* offsets   = (int*)alloc(B_SZ * 4);
  int* counts    = (int*)alloc(LMAX * 4);
  int* lists_    = (int*)alloc((size_t)LMAX * B_SZ * 4);
  u16* hbuf0     = (u16*)alloc((size_t)B_SZ * H_DIM * 2);
  u16* hbuf1     = (u16*)alloc((size_t)B_SZ * H_DIM * 2);
  u16* wih_bf    = (u16*)alloc((size_t)H3 * H_DIM * 2);
  u16* whh_bf    = (u16*)alloc((size_t)H3 * H_DIM * 2);
  u16* k_bf      = (u16*)alloc((size_t)B_SZ * H_DIM * 2);
  u16* x_bf      = (u16*)alloc((size_t)Mpad * H_DIM * 2);
  u16* gi        = (u16*)alloc((size_t)Mpad * H3 * 2);
  float* scores  = (float*)alloc((size_t)B_SZ * B_SZ * 4);
  float* row_loss= (float*)alloc(B_SZ * 4);
  if ((size_t)(p - (char*)d_ws) > ws_size) return;  // workspace too small (loud fail)

  prep_kernel<<<(H3 * H_DIM / 8) / 256, 256, 0, stream>>>(
      wih, whh, k_emb, q_emb, wih_bf, whh_bf, k_bf, hbuf0);
  convx_kernel<<<((size_t)Mpad * H_DIM / 8) / 256, 256, 0, stream>>>(inpn, x_bf, total);
  offsets_kernel<<<1, B_SZ, 0, stream>>>(lens, offsets);
  lists_kernel<<<LMAX, B_SZ, 0, stream>>>(lens, lists_, counts);

  gi_gemm_kernel<<<mtiles * 36, 256, 0, stream>>>(x_bf, wih_bf, bih, gi, mtiles);

  for (int t = 0; t < LMAX; ++t) {
    u16* hc = (t & 1) ? hbuf1 : hbuf0;
    u16* hn = (t & 1) ? hbuf0 : hbuf1;
    gh_step_kernel<<<192, 512, 0, stream>>>(
        hc, hn, whh_bf, gi, bhh, offsets, lists_, counts, t);
  }

  scores_kernel<<<dim3(B_SZ / 64, B_SZ / 64), 256, 0, stream>>>(
      hbuf0, hbuf1, lens, k_bf, scores);
  softmax_kernel<<<B_SZ, 256, 0, stream>>>(scores, row_loss);
  final_kernel<<<1, B_SZ, 0, stream>>>(row_loss, out);
}